// Round 1
// 1667.427 us; speedup vs baseline: 1.0557x; 1.0557x over previous
//
#include <hip/hip_runtime.h>

typedef __attribute__((ext_vector_type(8))) short short8;
typedef __attribute__((ext_vector_type(4))) float f32x4;
typedef __attribute__((ext_vector_type(4))) unsigned short us4;
typedef __attribute__((ext_vector_type(8))) unsigned short us8;

#define SLEN 2048
#define EDIM 1024
#define NH 16
#define HD 64

__device__ __forceinline__ unsigned short f2bf(float x) {
    unsigned int u = __builtin_bit_cast(unsigned int, x);
    u += 0x7FFFu + ((u >> 16) & 1u);
    return (unsigned short)(u >> 16);
}

// async global->LDS, 16B per lane; dst must be wave-uniform base (HW adds lane*16)
__device__ __forceinline__ void gload16(const unsigned short* g, unsigned short* l) {
    __builtin_amdgcn_global_load_lds(
        (const __attribute__((address_space(1))) unsigned int*)g,
        (__attribute__((address_space(3))) unsigned int*)l, 16, 0, 0);
}

// ---------------- fp32 -> bf16 convert (vectorized, grid-stride) ----------------
__global__ __launch_bounds__(256) void k_f32_to_bf16(const float* __restrict__ in,
                                                     unsigned short* __restrict__ out, int n4) {
    int i = blockIdx.x * blockDim.x + threadIdx.x;
    int stride = gridDim.x * blockDim.x;
    for (; i < n4; i += stride) {
        float4 v = ((const float4*)in)[i];
        us4 o;
        o.x = f2bf(v.x); o.y = f2bf(v.y); o.z = f2bf(v.z); o.w = f2bf(v.w);
        ((us4*)out)[i] = o;
    }
}

// ---------------- fp32 [1024x1024] -> bf16 transpose: Wt[n][k] = W[k][n] ----------------
__global__ void k_transpose_bf16(const float* __restrict__ W, unsigned short* __restrict__ Wt) {
    __shared__ float tile[32][33];
    int x = blockIdx.x * 32 + threadIdx.x;
    for (int i = threadIdx.y; i < 32; i += 8)
        tile[i][threadIdx.x] = W[(size_t)(blockIdx.y * 32 + i) * EDIM + x];
    __syncthreads();
    int xo = blockIdx.y * 32 + threadIdx.x;
    for (int i = threadIdx.y; i < 32; i += 8)
        Wt[(size_t)(blockIdx.x * 32 + i) * EDIM + xo] = f2bf(tile[threadIdx.x][i]);
}

// ---------------- QKV projection GEMM (m97 structure: global_load_lds, linear LDS) -------
// C[m][n] = sum_k X[m][k] * Wt[n][k]; M=8192, N=1024, K=1024; 128x128 tile, BK=32
// z=0: Q (scaled 1/8, head-major out), z=1: K (head-major out), z=2: V (transposed out)
__global__ __launch_bounds__(256) void k_gemm_qkv(
    const unsigned short* __restrict__ Xq, const unsigned short* __restrict__ Xk,
    const unsigned short* __restrict__ Xv, const unsigned short* __restrict__ Wqt,
    const unsigned short* __restrict__ Wkt, const unsigned short* __restrict__ Wvt,
    unsigned short* __restrict__ Qh, unsigned short* __restrict__ Kh,
    unsigned short* __restrict__ Vth) {
    __shared__ __attribute__((aligned(16))) unsigned short sA[128 * 32];
    __shared__ __attribute__((aligned(16))) unsigned short sB[128 * 32];
    int z = blockIdx.z;
    const unsigned short* X = (z == 0) ? Xq : ((z == 1) ? Xk : Xv);
    const unsigned short* Wt = (z == 0) ? Wqt : ((z == 1) ? Wkt : Wvt);
    int tid = threadIdx.x, lane = tid & 63, wave = tid >> 6;
    int l16 = lane & 15, g4 = lane >> 4;
    int wm = (wave >> 1) * 64, wn = (wave & 1) * 64;
    int m0 = blockIdx.y * 128, n0 = blockIdx.x * 128;
    int sr = lane >> 2, sc = (lane & 3) * 8;  // staging: row-in-chunk, col (elems)
    f32x4 acc[4][4] = {};
    for (int k0 = 0; k0 < EDIM; k0 += 32) {
        __syncthreads();
#pragma unroll
        for (int i = 0; i < 2; i++) {
            int c = wave * 2 + i;          // 1024B chunk = 16 rows of 64B
            int r = c * 16 + sr;
            gload16(X + (size_t)(m0 + r) * EDIM + k0 + sc, sA + c * 512);
            gload16(Wt + (size_t)(n0 + r) * EDIM + k0 + sc, sB + c * 512);
        }
        __syncthreads();
        short8 a[4], b[4];
#pragma unroll
        for (int mi = 0; mi < 4; mi++)
            a[mi] = *(const short8*)(sA + (wm + mi * 16 + l16) * 32 + g4 * 8);
#pragma unroll
        for (int ni = 0; ni < 4; ni++)
            b[ni] = *(const short8*)(sB + (wn + ni * 16 + l16) * 32 + g4 * 8);
#pragma unroll
        for (int mi = 0; mi < 4; mi++)
#pragma unroll
            for (int ni = 0; ni < 4; ni++)
                acc[mi][ni] =
                    __builtin_amdgcn_mfma_f32_16x16x32_bf16(a[mi], b[ni], acc[mi][ni], 0, 0, 0);
    }
    float scale = (z == 0) ? 0.125f : 1.0f;  // fold 1/sqrt(DK) into Q
#pragma unroll
    for (int mi = 0; mi < 4; mi++) {
        int mbase = m0 + wm + mi * 16 + g4 * 4;
#pragma unroll
        for (int ni = 0; ni < 4; ni++) {
            int n = n0 + wn + ni * 16 + l16;
            int h = n >> 6, d = n & 63;
            if (z < 2) {
                unsigned short* O = (z == 0) ? Qh : Kh;
#pragma unroll
                for (int r = 0; r < 4; r++) {
                    int m = mbase + r;
                    int bb = m >> 11, s = m & (SLEN - 1);
                    O[(((size_t)bb * NH + h) * SLEN + s) * HD + d] = f2bf(acc[mi][ni][r] * scale);
                }
            } else {
                int bb = mbase >> 11, s0 = mbase & (SLEN - 1);
                us4 pk;
                pk.x = f2bf(acc[mi][ni][0]);
                pk.y = f2bf(acc[mi][ni][1]);
                pk.z = f2bf(acc[mi][ni][2]);
                pk.w = f2bf(acc[mi][ni][3]);
                *(us4*)(Vth + (((size_t)bb * NH + h) * HD + d) * SLEN + s0) = pk;
            }
        }
    }
}

// ---------------- fused attention ----------------
// grid (S/128, B*H); each block: 128 q-rows (32/wave, two 16-row fragment sets),
// loop over 64-key blocks.
// phase 1: rowsum of exp(QK^T) (no max-sub: |scores| ~ O(3), exp is safe)
// phase 2: recompute, write normalized probs to attn, P->LDS->A-frag, PV MFMA.
__global__ __launch_bounds__(256) void k_attn(
    const unsigned short* __restrict__ Qh, const unsigned short* __restrict__ Kh,
    const unsigned short* __restrict__ Vth, const unsigned char* __restrict__ mask,
    float* __restrict__ attn, unsigned short* __restrict__ Ctx) {
    __shared__ __attribute__((aligned(16))) unsigned short sK[64 * 80];
    __shared__ __attribute__((aligned(16))) unsigned short sV[64 * 80];
    __shared__ __attribute__((aligned(16))) unsigned short sP[4][16 * 80];
    __shared__ __attribute__((aligned(16))) unsigned char sM[128 * 64];
    int tid = threadIdx.x, lane = tid & 63, wave = tid >> 6;
    int l16 = lane & 15, g4 = lane >> 4;
    int bh = blockIdx.y, b = bh >> 4, h = bh & 15;
    int q0 = blockIdx.x * 128;
    int qw = q0 + wave * 32;
    const unsigned short* Qbase = Qh + ((size_t)bh * SLEN + qw + l16) * HD;
    short8 aq[2][2];
#pragma unroll
    for (int s = 0; s < 2; s++) {
        aq[s][0] = *(const short8*)(Qbase + s * 16 * HD + g4 * 8);
        aq[s][1] = *(const short8*)(Qbase + s * 16 * HD + 32 + g4 * 8);
    }
    const size_t mbase = (size_t)b * SLEN * SLEN;
    float rs[2][4] = {};

    // ---- phase 1: row sums ----
    for (int kb = 0; kb < SLEN / 64; kb++) {
        int key0 = kb * 64;
        __syncthreads();
#pragma unroll
        for (int i = 0; i < 2; i++) {
            int u = tid + i * 256;
            int r = u >> 3, c = (u & 7) * 8;
            *(us8*)(sK + r * 80 + c) = *(const us8*)(Kh + ((size_t)bh * SLEN + key0 + r) * HD + c);
        }
        {
            int r = tid >> 1, c = (tid & 1) * 32;
            const unsigned char* mp = mask + mbase + (size_t)(q0 + r) * SLEN + key0 + c;
            *(uint4*)(sM + r * 64 + c) = *(const uint4*)(mp);
            *(uint4*)(sM + r * 64 + c + 16) = *(const uint4*)(mp + 16);
        }
        __syncthreads();
#pragma unroll
        for (int ni = 0; ni < 4; ni++) {
            short8 b0 = *(const short8*)(sK + (ni * 16 + l16) * 80 + g4 * 8);
            short8 b1 = *(const short8*)(sK + (ni * 16 + l16) * 80 + 32 + g4 * 8);
#pragma unroll
            for (int s = 0; s < 2; s++) {
                f32x4 c4 = {0.f, 0.f, 0.f, 0.f};
                c4 = __builtin_amdgcn_mfma_f32_16x16x32_bf16(aq[s][0], b0, c4, 0, 0, 0);
                c4 = __builtin_amdgcn_mfma_f32_16x16x32_bf16(aq[s][1], b1, c4, 0, 0, 0);
#pragma unroll
                for (int r = 0; r < 4; r++) {
                    int row = wave * 32 + s * 16 + g4 * 4 + r;
                    float p = sM[row * 64 + ni * 16 + l16] ? 0.0f : __expf(c4[r]);
                    rs[s][r] += p;
                }
            }
        }
    }
#pragma unroll
    for (int s = 0; s < 2; s++)
#pragma unroll
        for (int r = 0; r < 4; r++) {
            float v = rs[s][r];
            v += __shfl_xor(v, 1, 64);
            v += __shfl_xor(v, 2, 64);
            v += __shfl_xor(v, 4, 64);
            v += __shfl_xor(v, 8, 64);
            rs[s][r] = 1.0f / v;
        }

    // ---- phase 2: write attn + PV ----
    f32x4 accd[2][4] = {};
    for (int kb = 0; kb < SLEN / 64; kb++) {
        int key0 = kb * 64;
        __syncthreads();
#pragma unroll
        for (int i = 0; i < 2; i++) {
            int u = tid + i * 256;
            int r = u >> 3, c = (u & 7) * 8;
            *(us8*)(sK + r * 80 + c) = *(const us8*)(Kh + ((size_t)bh * SLEN + key0 + r) * HD + c);
            *(us8*)(sV + r * 80 + c) = *(const us8*)(Vth + ((size_t)bh * HD + r) * SLEN + key0 + c);
        }
        {
            int r = tid >> 1, c = (tid & 1) * 32;
            const unsigned char* mp = mask + mbase + (size_t)(q0 + r) * SLEN + key0 + c;
            *(uint4*)(sM + r * 64 + c) = *(const uint4*)(mp);
            *(uint4*)(sM + r * 64 + c + 16) = *(const uint4*)(mp + 16);
        }
        __syncthreads();
#pragma unroll
        for (int s = 0; s < 2; s++) {
#pragma unroll
            for (int ni = 0; ni < 4; ni++) {
                short8 b0 = *(const short8*)(sK + (ni * 16 + l16) * 80 + g4 * 8);
                short8 b1 = *(const short8*)(sK + (ni * 16 + l16) * 80 + 32 + g4 * 8);
                f32x4 c4 = {0.f, 0.f, 0.f, 0.f};
                c4 = __builtin_amdgcn_mfma_f32_16x16x32_bf16(aq[s][0], b0, c4, 0, 0, 0);
                c4 = __builtin_amdgcn_mfma_f32_16x16x32_bf16(aq[s][1], b1, c4, 0, 0, 0);
#pragma unroll
                for (int r = 0; r < 4; r++) {
                    int qr = g4 * 4 + r;
                    int row = wave * 32 + s * 16 + qr;
                    float p = sM[row * 64 + ni * 16 + l16] ? 0.0f
                                                          : __expf(c4[r]) * rs[s][r];
                    attn[((size_t)bh * SLEN + q0 + row) * SLEN + key0 + ni * 16 + l16] = p;
                    sP[wave][qr * 80 + ni * 16 + l16] = f2bf(p);
                }
            }
            // P (C-layout) -> A-layout via per-wave LDS round-trip (same-wave dep)
            short8 ap0 = *(const short8*)(&sP[wave][0] + l16 * 80 + g4 * 8);
            short8 ap1 = *(const short8*)(&sP[wave][0] + l16 * 80 + 32 + g4 * 8);
#pragma unroll
            for (int nd = 0; nd < 4; nd++) {
                short8 v0 = *(const short8*)(sV + (nd * 16 + l16) * 80 + g4 * 8);
                short8 v1 = *(const short8*)(sV + (nd * 16 + l16) * 80 + 32 + g4 * 8);
                accd[s][nd] = __builtin_amdgcn_mfma_f32_16x16x32_bf16(ap0, v0, accd[s][nd], 0, 0, 0);
                accd[s][nd] = __builtin_amdgcn_mfma_f32_16x16x32_bf16(ap1, v1, accd[s][nd], 0, 0, 0);
            }
        }
    }
    // context out: [b, s, h*64+d] bf16
#pragma unroll
    for (int s = 0; s < 2; s++)
#pragma unroll
        for (int nd = 0; nd < 4; nd++)
#pragma unroll
            for (int r = 0; r < 4; r++) {
                int srow = qw + s * 16 + g4 * 4 + r;
                Ctx[((size_t)b * SLEN + srow) * EDIM + h * HD + nd * 16 + l16] =
                    f2bf(accd[s][nd][r]);
            }
}

// ---------------- output projection GEMM + residual (m97 structure) ----------------
__global__ __launch_bounds__(256) void k_gemm_out(const unsigned short* __restrict__ Ctx,
                                                  const unsigned short* __restrict__ Wot,
                                                  const float* __restrict__ resid,
                                                  float* __restrict__ xout) {
    __shared__ __attribute__((aligned(16))) unsigned short sA[128 * 32];
    __shared__ __attribute__((aligned(16))) unsigned short sB[128 * 32];
    int tid = threadIdx.x, lane = tid & 63, wave = tid >> 6;
    int l16 = lane & 15, g4 = lane >> 4;
    int wm = (wave >> 1) * 64, wn = (wave & 1) * 64;
    int m0 = blockIdx.y * 128, n0 = blockIdx.x * 128;
    int sr = lane >> 2, sc = (lane & 3) * 8;
    f32x4 acc[4][4] = {};
    for (int k0 = 0; k0 < EDIM; k0 += 32) {
        __syncthreads();
#pragma unroll
        for (int i = 0; i < 2; i++) {
            int c = wave * 2 + i;
            int r = c * 16 + sr;
            gload16(Ctx + (size_t)(m0 + r) * EDIM + k0 + sc, sA + c * 512);
            gload16(Wot + (size_t)(n0 + r) * EDIM + k0 + sc, sB + c * 512);
        }
        __syncthreads();
        short8 a[4], b[4];
#pragma unroll
        for (int mi = 0; mi < 4; mi++)
            a[mi] = *(const short8*)(sA + (wm + mi * 16 + l16) * 32 + g4 * 8);
#pragma unroll
        for (int ni = 0; ni < 4; ni++)
            b[ni] = *(const short8*)(sB + (wn + ni * 16 + l16) * 32 + g4 * 8);
#pragma unroll
        for (int mi = 0; mi < 4; mi++)
#pragma unroll
            for (int ni = 0; ni < 4; ni++)
                acc[mi][ni] =
                    __builtin_amdgcn_mfma_f32_16x16x32_bf16(a[mi], b[ni], acc[mi][ni], 0, 0, 0);
    }
#pragma unroll
    for (int mi = 0; mi < 4; mi++)
#pragma unroll
        for (int ni = 0; ni < 4; ni++)
#pragma unroll
            for (int r = 0; r < 4; r++) {
                int m = m0 + wm + mi * 16 + g4 * 4 + r;
                int n = n0 + wn + ni * 16 + l16;
                size_t idx = (size_t)m * EDIM + n;
                xout[idx] = acc[mi][ni][r] + resid[idx];
            }
}

// ---------------- LayerNorm: one block per row of 1024 ----------------
__global__ __launch_bounds__(256) void k_ln(const float* __restrict__ x,
                                            const float* __restrict__ gamma,
                                            const float* __restrict__ beta,
                                            float* __restrict__ out) {
    int row = blockIdx.x, tid = threadIdx.x, lane = tid & 63, wave = tid >> 6;
    float4 v = ((const float4*)(x + (size_t)row * EDIM))[tid];
    float s = v.x + v.y + v.z + v.w;
    float ss = v.x * v.x + v.y * v.y + v.z * v.z + v.w * v.w;
#pragma unroll
    for (int m = 1; m < 64; m <<= 1) {
        s += __shfl_xor(s, m, 64);
        ss += __shfl_xor(ss, m, 64);
    }
    __shared__ float as[4], ass[4];
    if (lane == 0) { as[wave] = s; ass[wave] = ss; }
    __syncthreads();
    float sum = as[0] + as[1] + as[2] + as[3];
    float ssum = ass[0] + ass[1] + ass[2] + ass[3];
    float mean = sum * (1.0f / EDIM);
    float var = ssum * (1.0f / EDIM) - mean * mean;
    float rstd = rsqrtf(var + 1e-5f);
    float4 g = ((const float4*)gamma)[tid];
    float4 bt = ((const float4*)beta)[tid];
    float4 o;
    o.x = (v.x - mean) * rstd * g.x + bt.x;
    o.y = (v.y - mean) * rstd * g.y + bt.y;
    o.z = (v.z - mean) * rstd * g.z + bt.z;
    o.w = (v.w - mean) * rstd * g.w + bt.w;
    ((float4*)(out + (size_t)row * EDIM))[tid] = o;
}

extern "C" void kernel_launch(void* const* d_in, const int* in_sizes, int n_in, void* d_out,
                              int out_size, void* d_ws, size_t ws_size, hipStream_t stream) {
    const float* inQ = (const float*)d_in[0];
    const float* inK = (const float*)d_in[1];
    const float* inV = (const float*)d_in[2];
    const unsigned char* mask = (const unsigned char*)d_in[3];
    const float* WQ = (const float*)d_in[4];
    const float* WK = (const float*)d_in[5];
    const float* WV = (const float*)d_in[6];
    const float* WO = (const float*)d_in[7];
    const float* gamma = (const float*)d_in[8];
    const float* beta = (const float*)d_in[9];
    float* out = (float*)d_out;
    float* attn = out + (size_t)4 * SLEN * EDIM;  // outputs concat: [out | attn]
    char* ws = (char*)d_ws;

    // ws layout (bytes); peak ~104 MB with overlays
    unsigned short* Xq = (unsigned short*)(ws);                      // 16 MB
    unsigned short* Xk = (unsigned short*)(ws + 16777216);           // 16 MB
    unsigned short* Xv = (unsigned short*)(ws + 2 * 16777216);       // 16 MB
    unsigned short* Wqt = (unsigned short*)(ws + 3 * 16777216);      // 2 MB x4
    unsigned short* Wkt = Wqt + 1048576;
    unsigned short* Wvt = Wkt + 1048576;
    unsigned short* Wot = Wvt + 1048576;
    unsigned short* Qh = (unsigned short*)(ws + 3 * 16777216 + 4 * 2097152);  // 16 MB
    unsigned short* Kh = Qh + 8388608;                                        // 16 MB
    unsigned short* Vth = Kh + 8388608;                                       // 16 MB
    unsigned short* Ctx = Xq;                       // overlay (Xq dead after QKV GEMM)
    float* xout = (float*)(ws + 16777216);          // overlay Xk..Xv (dead after QKV GEMM)

    int n4 = (4 * SLEN * EDIM) / 4;
    k_f32_to_bf16<<<2048, 256, 0, stream>>>(inQ, Xq, n4);
    k_f32_to_bf16<<<2048, 256, 0, stream>>>(inK, Xk, n4);
    k_f32_to_bf16<<<2048, 256, 0, stream>>>(inV, Xv, n4);
    dim3 tb(32, 8);
    k_transpose_bf16<<<dim3(32, 32), tb, 0, stream>>>(WQ, Wqt);
    k_transpose_bf16<<<dim3(32, 32), tb, 0, stream>>>(WK, Wkt);
    k_transpose_bf16<<<dim3(32, 32), tb, 0, stream>>>(WV, Wvt);
    k_transpose_bf16<<<dim3(32, 32), tb, 0, stream>>>(WO, Wot);
    k_gemm_qkv<<<dim3(8, 64, 3), 256, 0, stream>>>(Xq, Xk, Xv, Wqt, Wkt, Wvt, Qh, Kh, Vth);
    k_attn<<<dim3(SLEN / 128, 4 * NH), 256, 0, stream>>>(Qh, Kh, Vth, mask, attn, Ctx);
    k_gemm_out<<<dim3(8, 64), 256, 0, stream>>>(Ctx, Wot, inQ, xout);
    k_ln<<<4 * SLEN, 256, 0, stream>>>(xout, gamma, beta, out);
}